// Round 18
// baseline (29.753 us; speedup 1.0000x reference)
//
#include <hip/hip_runtime.h>

typedef __attribute__((ext_vector_type(8))) short bf16x8;
typedef __attribute__((ext_vector_type(4))) float f32x4;

#define C_DIM 512
#define HID   256
#define B_DIM 8
#define L_DIM 196
#define GEMM_BLOCKS 256         // 8 b x 4 mt(64m) x 2 side x 4 ntp(64n)
#define ROWS  14                // i-rows per wave (pair)
#define NJC   14
#define JCL   14
#define PAIR_BLOCKS ((B_DIM*NJC*ROWS)/4)    // 392 = 49*8
#define P_ELEMS (B_DIM*L_DIM*HID)

// f32 -> bf16 bits, round-to-nearest (ties up)
__device__ __forceinline__ short bf16r(float x) {
  unsigned u = __builtin_bit_cast(unsigned, x);
  return (short)((u + 0x8000u) >> 16);
}

// Phase 1 v7: 64m x 64n tile, K-split x8 (8 waves, 512 thr), XCD-local.
//   p[b,l,h] = sum_c f[b,c,l] * W[c,h]   (+ b1[h] for side 0)
// r17's gather savings (262K instrs) + restored TLP: 2048 waves = 2/SIMD
// (r17's 4-wave variant was 1/SIMD -> latency-exposed, +4.9us).
// Per wave: 2 ksteps x (64 gathers -> 16 MFMA); 3-round LDS tree-combine.
__global__ __launch_bounds__(512) void gemm_p_mfma(
    const float* __restrict__ f1, const float* __restrict__ f2,
    const float* __restrict__ W1, const float* __restrict__ b1,
    const float* __restrict__ b2,
    float* __restrict__ p1, float* __restrict__ p2,
    float* __restrict__ out) {
  // init output accumulators (pair_kernel atomicAdds into them)
  if (blockIdx.x == 0 && threadIdx.x < B_DIM)
    out[threadIdx.x] = (float)(L_DIM * L_DIM) * b2[0];

  const int b    = blockIdx.x & 7;              // XCD-co-located batch
  const int idx  = blockIdx.x >> 3;             // 0..31
  const int ntp  = idx & 3;                     // 0..3 (64-wide n tile)
  const int ms   = idx >> 2;                    // 0..7
  const int side = ms & 1;
  const int mt   = ms >> 1;                     // 64-row m-tile, 0..3

  const float* __restrict__ f = side ? f2 : f1;
  const float* __restrict__ W = W1 + side * C_DIM * HID;
  float* __restrict__ p = side ? p2 : p1;

  const int tid  = threadIdx.x;
  const int kq   = tid >> 6;                    // wave = k-eighth 0..7
  const int lane = tid & 63;
  const int g    = lane >> 4;                   // k-subgroup 0..3
  const int mcol = lane & 15;

  int aoff[4];
  #pragma unroll
  for (int mi = 0; mi < 4; ++mi) {
    const int rib = mt * 64 + mi * 16 + mcol;   // 0..255 (tail clamped)
    const int l = rib < L_DIM ? rib : L_DIM - 1;
    aoff[mi] = (b * C_DIM) * L_DIM + l;
  }
  const int h0 = ntp * 64 + mcol;               // + ni*16

  f32x4 acc[4][4];
  #pragma unroll
  for (int mi = 0; mi < 4; ++mi)
    #pragma unroll
    for (int ni = 0; ni < 4; ++ni)
      acc[mi][ni] = (f32x4){0.f, 0.f, 0.f, 0.f};

  #pragma unroll
  for (int ks = 0; ks < 2; ++ks) {
    const int k0 = kq * 64 + ks * 32 + g * 8;   // this lane's 8 k's
    bf16x8 afr[4], bfr[4];
    #pragma unroll
    for (int mi = 0; mi < 4; ++mi) {            // A shared across 4 n-frags
      const float* __restrict__ pa = f + aoff[mi] + k0 * L_DIM;
      #pragma unroll
      for (int i = 0; i < 8; ++i) afr[mi][i] = bf16r(pa[i * L_DIM]);
    }
    #pragma unroll
    for (int ni = 0; ni < 4; ++ni) {            // B shared across 4 m-frags
      const float* __restrict__ pb = W + k0 * HID + h0 + ni * 16;
      #pragma unroll
      for (int i = 0; i < 8; ++i) bfr[ni][i] = bf16r(pb[i * HID]);
    }
    #pragma unroll
    for (int mi = 0; mi < 4; ++mi)
      #pragma unroll
      for (int ni = 0; ni < 4; ++ni)
        acc[mi][ni] = __builtin_amdgcn_mfma_f32_16x16x32_bf16(
            afr[mi], bfr[ni], acc[mi][ni], 0, 0, 0);
  }

  // 3-round tree-combine of 8 k-eighth waves; comb[buf][q=mi*4+ni][lane]
  __shared__ float4 comb[4][16][64];            // 64 KB (b128 lane-major)
  if (kq >= 4) {                                // R1: 4..7 -> bufs 0..3
    #pragma unroll
    for (int mi = 0; mi < 4; ++mi)
      #pragma unroll
      for (int ni = 0; ni < 4; ++ni)
        comb[kq - 4][mi * 4 + ni][lane] = *(float4*)&acc[mi][ni];
  }
  __syncthreads();
  if (kq < 4) {
    #pragma unroll
    for (int mi = 0; mi < 4; ++mi)
      #pragma unroll
      for (int ni = 0; ni < 4; ++ni) {
        const float4 o = comb[kq][mi * 4 + ni][lane];
        acc[mi][ni][0] += o.x; acc[mi][ni][1] += o.y;
        acc[mi][ni][2] += o.z; acc[mi][ni][3] += o.w;
      }
  }
  __syncthreads();
  if (kq == 2 || kq == 3) {                     // R2: 2,3 -> bufs 0,1
    #pragma unroll
    for (int mi = 0; mi < 4; ++mi)
      #pragma unroll
      for (int ni = 0; ni < 4; ++ni)
        comb[kq - 2][mi * 4 + ni][lane] = *(float4*)&acc[mi][ni];
  }
  __syncthreads();
  if (kq < 2) {
    #pragma unroll
    for (int mi = 0; mi < 4; ++mi)
      #pragma unroll
      for (int ni = 0; ni < 4; ++ni) {
        const float4 o = comb[kq][mi * 4 + ni][lane];
        acc[mi][ni][0] += o.x; acc[mi][ni][1] += o.y;
        acc[mi][ni][2] += o.z; acc[mi][ni][3] += o.w;
      }
  }
  __syncthreads();
  if (kq == 1) {                                // R3: 1 -> buf 0
    #pragma unroll
    for (int mi = 0; mi < 4; ++mi)
      #pragma unroll
      for (int ni = 0; ni < 4; ++ni)
        comb[0][mi * 4 + ni][lane] = *(float4*)&acc[mi][ni];
  }
  __syncthreads();
  if (kq == 0) {
    // C/D layout (verified): col = lane&15, row = g*4 + reg
    #pragma unroll
    for (int mi = 0; mi < 4; ++mi) {
      const int rib0 = mt * 64 + mi * 16 + g * 4;
      #pragma unroll
      for (int ni = 0; ni < 4; ++ni) {
        const int h = h0 + ni * 16;
        const float bias = side ? 0.0f : b1[h];
        const float4 o = comb[0][mi * 4 + ni][lane];
        const float v0 = acc[mi][ni][0] + o.x + bias;
        const float v1 = acc[mi][ni][1] + o.y + bias;
        const float v2 = acc[mi][ni][2] + o.z + bias;
        const float v3 = acc[mi][ni][3] + o.w + bias;
        if (rib0 + 0 < L_DIM) p[(b * L_DIM + rib0 + 0) * HID + h] = v0;
        if (rib0 + 1 < L_DIM) p[(b * L_DIM + rib0 + 1) * HID + h] = v1;
        if (rib0 + 2 < L_DIM) p[(b * L_DIM + rib0 + 2) * HID + h] = v2;
        if (rib0 + 3 < L_DIM) p[(b * L_DIM + rib0 + 3) * HID + h] = v3;
      }
    }
  }
}

// Phase 2 (r16 exact): bid&7 = b -> XCD-local; wave = 14 i x 14 j;
// block-sum -> ONE atomicAdd into out[b].
__global__ __launch_bounds__(256) void pair_kernel(
    const float* __restrict__ p1, const float* __restrict__ p2,
    const float* __restrict__ W2, float* __restrict__ out) {
  const int lane = threadIdx.x & 63;
  const int w    = threadIdx.x >> 6;
  const int b    = blockIdx.x & 7;              // XCD-co-located batch
  const int idx  = blockIdx.x >> 3;             // 0..48
  const int r4   = idx * 4 + w;                 // 0..195
  const int jc   = r4 / ROWS;                   // 0..13
  const int wi   = r4 % ROWS;                   // 0..13

  const float4 wv = *(const float4*)(W2 + lane * 4);
  const float* __restrict__ p1b = p1 + (b * L_DIM) * HID + lane * 4;

  float4 a[ROWS];
  #pragma unroll
  for (int k = 0; k < ROWS; ++k)
    a[k] = *(const float4*)(p1b + (wi + k * ROWS) * HID);  // i = wi + k*14

  float s[ROWS];
  #pragma unroll
  for (int k = 0; k < ROWS; ++k) s[k] = 0.0f;

  const float4* __restrict__ vp =
      (const float4*)(p2 + (b * L_DIM + jc * JCL) * HID) + lane;

#define PAIR_BODY(vv)                                            \
  {                                                              \
    _Pragma("unroll")                                            \
    for (int k = 0; k < ROWS; ++k) {                             \
      s[k] = fmaf(fmaxf(a[k].x + (vv).x, 0.f), wv.x, s[k]);      \
      s[k] = fmaf(fmaxf(a[k].y + (vv).y, 0.f), wv.y, s[k]);      \
      s[k] = fmaf(fmaxf(a[k].z + (vv).z, 0.f), wv.z, s[k]);      \
      s[k] = fmaf(fmaxf(a[k].w + (vv).w, 0.f), wv.w, s[k]);      \
    }                                                            \
  }

  // two 7-deep batches: 7 loads in flight, then compute
  float4 vv[7];
  #pragma unroll
  for (int j = 0; j < 7; ++j) vv[j] = vp[j * (HID / 4)];
  #pragma unroll
  for (int j = 0; j < 7; ++j) PAIR_BODY(vv[j]);
  #pragma unroll
  for (int j = 0; j < 7; ++j) vv[j] = vp[(7 + j) * (HID / 4)];
  #pragma unroll
  for (int j = 0; j < 7; ++j) PAIR_BODY(vv[j]);
#undef PAIR_BODY

  // collapse rows (13 adds), then one 6-step wave reduce
  float t = 0.0f;
  #pragma unroll
  for (int k = 0; k < ROWS; ++k) t += s[k];
  #pragma unroll
  for (int off = 32; off > 0; off >>= 1) t += __shfl_down(t, off);

  __shared__ float sred[4];
  if (lane == 0) sred[w] = t;
  __syncthreads();
  if (threadIdx.x == 0)
    atomicAdd(&out[b], sred[0] + sred[1] + sred[2] + sred[3]);  // 392 total
}

extern "C" void kernel_launch(void* const* d_in, const int* in_sizes, int n_in,
                              void* d_out, int out_size, void* d_ws, size_t ws_size,
                              hipStream_t stream) {
  const float* f1 = (const float*)d_in[0];   // [B, C, 14, 14]
  const float* f2 = (const float*)d_in[1];
  const float* W1 = (const float*)d_in[2];   // [2C, HID]
  const float* b1 = (const float*)d_in[3];   // [HID]
  const float* W2 = (const float*)d_in[4];   // [HID, 1]
  const float* b2 = (const float*)d_in[5];   // [1]
  float* out = (float*)d_out;                // [B, 1]

  float* p1 = (float*)d_ws;
  float* p2 = p1 + P_ELEMS;

  gemm_p_mfma<<<GEMM_BLOCKS, 512, 0, stream>>>(f1, f2, W1, b1, b2, p1, p2, out);

  pair_kernel<<<PAIR_BLOCKS, 256, 0, stream>>>(p1, p2, W2, out);
}

// Round 19
// 24.345 us; speedup vs baseline: 1.2221x; 1.2221x over previous
//
#include <hip/hip_runtime.h>

typedef __attribute__((ext_vector_type(8))) short bf16x8;
typedef __attribute__((ext_vector_type(4))) float f32x4;

#define C_DIM 512
#define HID   256
#define B_DIM 8
#define L_DIM 196
#define GEMM_BLOCKS 448         // 8 b x 7 mt x 2 side x 4 ntp (64-wide n)
#define ROWS  14                // i-rows per wave (pair)
#define NJC   14
#define JCL   14
#define PAIR_BLOCKS ((B_DIM*NJC*ROWS)/4)    // 392 = 49*8
#define P_ELEMS (B_DIM*L_DIM*HID)

// f32 -> bf16 bits, round-to-nearest (ties up)
__device__ __forceinline__ short bf16r(float x) {
  unsigned u = __builtin_bit_cast(unsigned, x);
  return (short)((u + 0x8000u) >> 16);
}

// Phase 1 (r16 exact — champion config): MFMA bf16, K-split x4, XCD-local.
//   p[b,l,h] = sum_c f[b,c,l] * W[c,h]   (+ b1[h] for side 0)
// bid&7 = b -> all blocks of batch b on XCD b. Block = one 32m x 64n tile;
// A-fragments shared across 4 n-frags. Empirical optimum of the
// gather-count x TLP x tail-waste surface (r12/r16/r17/r18 probes).
__global__ __launch_bounds__(256) void gemm_p_mfma(
    const float* __restrict__ f1, const float* __restrict__ f2,
    const float* __restrict__ W1, const float* __restrict__ b1,
    const float* __restrict__ b2,
    float* __restrict__ p1, float* __restrict__ p2,
    float* __restrict__ out) {
  // init output accumulators (pair_kernel atomicAdds into them)
  if (blockIdx.x == 0 && threadIdx.x < B_DIM)
    out[threadIdx.x] = (float)(L_DIM * L_DIM) * b2[0];

  const int b    = blockIdx.x & 7;              // XCD-co-located batch
  const int idx  = blockIdx.x >> 3;             // 0..55
  const int ms   = idx >> 2;                    // 0..13
  const int ntp  = idx & 3;                     // 0..3 (64-wide n tile)
  const int side = ms & 1;
  const int mt   = ms >> 1;                     // m-tile within batch, 0..6

  const float* __restrict__ f = side ? f2 : f1;
  const float* __restrict__ W = W1 + side * C_DIM * HID;
  float* __restrict__ p = side ? p2 : p1;

  const int tid  = threadIdx.x;
  const int kq   = tid >> 6;                    // wave = k-quarter 0..3
  const int lane = tid & 63;
  const int g    = lane >> 4;                   // k-subgroup 0..3
  const int mcol = lane & 15;

  int aoff[2];
  #pragma unroll
  for (int mi = 0; mi < 2; ++mi) {
    const int rib = mt * 32 + mi * 16 + mcol;   // 0..223 (tail clamped)
    const int l = rib < L_DIM ? rib : L_DIM - 1;
    aoff[mi] = (b * C_DIM) * L_DIM + l;
  }
  const int h0 = ntp * 64 + mcol;               // + ni*16

  f32x4 acc[2][4];
  #pragma unroll
  for (int mi = 0; mi < 2; ++mi)
    #pragma unroll
    for (int ni = 0; ni < 4; ++ni)
      acc[mi][ni] = (f32x4){0.f, 0.f, 0.f, 0.f};

  #pragma unroll
  for (int ks = 0; ks < 4; ++ks) {
    const int k0 = kq * 128 + ks * 32 + g * 8;  // this lane's 8 k's
    bf16x8 afr[2], bfr[4];
    #pragma unroll
    for (int mi = 0; mi < 2; ++mi) {
      const float* __restrict__ pa = f + aoff[mi] + k0 * L_DIM;
      #pragma unroll
      for (int i = 0; i < 8; ++i) afr[mi][i] = bf16r(pa[i * L_DIM]);
    }
    #pragma unroll
    for (int ni = 0; ni < 4; ++ni) {            // A shared across 4 n-frags
      const float* __restrict__ pb = W + k0 * HID + h0 + ni * 16;
      #pragma unroll
      for (int i = 0; i < 8; ++i) bfr[ni][i] = bf16r(pb[i * HID]);
    }
    #pragma unroll
    for (int mi = 0; mi < 2; ++mi)
      #pragma unroll
      for (int ni = 0; ni < 4; ++ni)
        acc[mi][ni] = __builtin_amdgcn_mfma_f32_16x16x32_bf16(
            afr[mi], bfr[ni], acc[mi][ni], 0, 0, 0);
  }

  // tree-combine 4 k-quarter waves (32 floats/lane, idx = mi*16 + ni*4 + reg)
  __shared__ float comb[2][64][33];             // 16.9 KB
  if (kq >= 2) {
    #pragma unroll
    for (int mi = 0; mi < 2; ++mi)
      #pragma unroll
      for (int ni = 0; ni < 4; ++ni)
        *(float4*)&comb[kq - 2][lane][mi * 16 + ni * 4] = *(float4*)&acc[mi][ni];
  }
  __syncthreads();
  if (kq < 2) {
    #pragma unroll
    for (int mi = 0; mi < 2; ++mi)
      #pragma unroll
      for (int ni = 0; ni < 4; ++ni) {
        const float4 o = *(const float4*)&comb[kq][lane][mi * 16 + ni * 4];
        acc[mi][ni][0] += o.x; acc[mi][ni][1] += o.y;
        acc[mi][ni][2] += o.z; acc[mi][ni][3] += o.w;
      }
  }
  __syncthreads();
  if (kq == 1) {
    #pragma unroll
    for (int mi = 0; mi < 2; ++mi)
      #pragma unroll
      for (int ni = 0; ni < 4; ++ni)
        *(float4*)&comb[0][lane][mi * 16 + ni * 4] = *(float4*)&acc[mi][ni];
  }
  __syncthreads();
  if (kq == 0) {
    // C/D layout (verified): col = lane&15, row = g*4 + reg
    #pragma unroll
    for (int mi = 0; mi < 2; ++mi) {
      const int rib0 = mt * 32 + mi * 16 + g * 4;
      #pragma unroll
      for (int ni = 0; ni < 4; ++ni) {
        const int h = h0 + ni * 16;
        const float bias = side ? 0.0f : b1[h];
        const float4 o = *(const float4*)&comb[0][lane][mi * 16 + ni * 4];
        const float v0 = acc[mi][ni][0] + o.x + bias;
        const float v1 = acc[mi][ni][1] + o.y + bias;
        const float v2 = acc[mi][ni][2] + o.z + bias;
        const float v3 = acc[mi][ni][3] + o.w + bias;
        if (rib0 + 0 < L_DIM) p[(b * L_DIM + rib0 + 0) * HID + h] = v0;
        if (rib0 + 1 < L_DIM) p[(b * L_DIM + rib0 + 1) * HID + h] = v1;
        if (rib0 + 2 < L_DIM) p[(b * L_DIM + rib0 + 2) * HID + h] = v2;
        if (rib0 + 3 < L_DIM) p[(b * L_DIM + rib0 + 3) * HID + h] = v3;
      }
    }
  }
}

// Phase 2 (r16 exact): bid&7 = b -> XCD-local; wave = 14 i x 14 j;
// block-sum -> ONE atomicAdd into out[b].
__global__ __launch_bounds__(256) void pair_kernel(
    const float* __restrict__ p1, const float* __restrict__ p2,
    const float* __restrict__ W2, float* __restrict__ out) {
  const int lane = threadIdx.x & 63;
  const int w    = threadIdx.x >> 6;
  const int b    = blockIdx.x & 7;              // XCD-co-located batch
  const int idx  = blockIdx.x >> 3;             // 0..48
  const int r4   = idx * 4 + w;                 // 0..195
  const int jc   = r4 / ROWS;                   // 0..13
  const int wi   = r4 % ROWS;                   // 0..13

  const float4 wv = *(const float4*)(W2 + lane * 4);
  const float* __restrict__ p1b = p1 + (b * L_DIM) * HID + lane * 4;

  float4 a[ROWS];
  #pragma unroll
  for (int k = 0; k < ROWS; ++k)
    a[k] = *(const float4*)(p1b + (wi + k * ROWS) * HID);  // i = wi + k*14

  float s[ROWS];
  #pragma unroll
  for (int k = 0; k < ROWS; ++k) s[k] = 0.0f;

  const float4* __restrict__ vp =
      (const float4*)(p2 + (b * L_DIM + jc * JCL) * HID) + lane;

#define PAIR_BODY(vv)                                            \
  {                                                              \
    _Pragma("unroll")                                            \
    for (int k = 0; k < ROWS; ++k) {                             \
      s[k] = fmaf(fmaxf(a[k].x + (vv).x, 0.f), wv.x, s[k]);      \
      s[k] = fmaf(fmaxf(a[k].y + (vv).y, 0.f), wv.y, s[k]);      \
      s[k] = fmaf(fmaxf(a[k].z + (vv).z, 0.f), wv.z, s[k]);      \
      s[k] = fmaf(fmaxf(a[k].w + (vv).w, 0.f), wv.w, s[k]);      \
    }                                                            \
  }

  // two 7-deep batches: 7 loads in flight, then compute
  float4 vv[7];
  #pragma unroll
  for (int j = 0; j < 7; ++j) vv[j] = vp[j * (HID / 4)];
  #pragma unroll
  for (int j = 0; j < 7; ++j) PAIR_BODY(vv[j]);
  #pragma unroll
  for (int j = 0; j < 7; ++j) vv[j] = vp[(7 + j) * (HID / 4)];
  #pragma unroll
  for (int j = 0; j < 7; ++j) PAIR_BODY(vv[j]);
#undef PAIR_BODY

  // collapse rows (13 adds), then one 6-step wave reduce
  float t = 0.0f;
  #pragma unroll
  for (int k = 0; k < ROWS; ++k) t += s[k];
  #pragma unroll
  for (int off = 32; off > 0; off >>= 1) t += __shfl_down(t, off);

  __shared__ float sred[4];
  if (lane == 0) sred[w] = t;
  __syncthreads();
  if (threadIdx.x == 0)
    atomicAdd(&out[b], sred[0] + sred[1] + sred[2] + sred[3]);  // 392 total
}

extern "C" void kernel_launch(void* const* d_in, const int* in_sizes, int n_in,
                              void* d_out, int out_size, void* d_ws, size_t ws_size,
                              hipStream_t stream) {
  const float* f1 = (const float*)d_in[0];   // [B, C, 14, 14]
  const float* f2 = (const float*)d_in[1];
  const float* W1 = (const float*)d_in[2];   // [2C, HID]
  const float* b1 = (const float*)d_in[3];   // [HID]
  const float* W2 = (const float*)d_in[4];   // [HID, 1]
  const float* b2 = (const float*)d_in[5];   // [1]
  float* out = (float*)d_out;                // [B, 1]

  float* p1 = (float*)d_ws;
  float* p2 = p1 + P_ELEMS;

  gemm_p_mfma<<<GEMM_BLOCKS, 256, 0, stream>>>(f1, f2, W1, b1, b2, p1, p2, out);

  pair_kernel<<<PAIR_BLOCKS, 256, 0, stream>>>(p1, p2, W2, out);
}

// Round 20
// 22.815 us; speedup vs baseline: 1.3041x; 1.0671x over previous
//
#include <hip/hip_runtime.h>

typedef __attribute__((ext_vector_type(8))) short bf16x8;
typedef __attribute__((ext_vector_type(4))) float f32x4;
typedef _Float16 f16x2 __attribute__((ext_vector_type(2)));
typedef _Float16 f16x4 __attribute__((ext_vector_type(4)));

#define C_DIM 512
#define HID   256
#define B_DIM 8
#define L_DIM 196
#define GEMM_BLOCKS 448         // 8 b x 7 mt x 2 side x 4 ntp (64-wide n)
#define ROWS  14                // i-rows per wave (pair)
#define NJC   14
#define JCL   14
#define PAIR_BLOCKS ((B_DIM*NJC*ROWS)/4)    // 392 = 49*8
#define P_ELEMS (B_DIM*L_DIM*HID)

// f32 -> bf16 bits, round-to-nearest (ties up)
__device__ __forceinline__ short bf16r(float x) {
  unsigned u = __builtin_bit_cast(unsigned, x);
  return (short)((u + 0x8000u) >> 16);
}

// Phase 1 (r16 structure; epilogue stores p as fp16): MFMA bf16, K-split x4,
// XCD-local (bid&7 = b). Block = one 32m x 64n tile; A-frags shared across
// 4 n-frags. p values ~±3 -> fp16 err ~1e-3 vs threshold 115.84.
__global__ __launch_bounds__(256) void gemm_p_mfma(
    const float* __restrict__ f1, const float* __restrict__ f2,
    const float* __restrict__ W1, const float* __restrict__ b1,
    const float* __restrict__ b2,
    _Float16* __restrict__ p1, _Float16* __restrict__ p2,
    float* __restrict__ out) {
  // init output accumulators (pair_kernel atomicAdds into them)
  if (blockIdx.x == 0 && threadIdx.x < B_DIM)
    out[threadIdx.x] = (float)(L_DIM * L_DIM) * b2[0];

  const int b    = blockIdx.x & 7;              // XCD-co-located batch
  const int idx  = blockIdx.x >> 3;             // 0..55
  const int ms   = idx >> 2;                    // 0..13
  const int ntp  = idx & 3;                     // 0..3 (64-wide n tile)
  const int side = ms & 1;
  const int mt   = ms >> 1;                     // m-tile within batch, 0..6

  const float* __restrict__ f = side ? f2 : f1;
  const float* __restrict__ W = W1 + side * C_DIM * HID;
  _Float16* __restrict__ p = side ? p2 : p1;

  const int tid  = threadIdx.x;
  const int kq   = tid >> 6;                    // wave = k-quarter 0..3
  const int lane = tid & 63;
  const int g    = lane >> 4;                   // k-subgroup 0..3
  const int mcol = lane & 15;

  int aoff[2];
  #pragma unroll
  for (int mi = 0; mi < 2; ++mi) {
    const int rib = mt * 32 + mi * 16 + mcol;   // 0..223 (tail clamped)
    const int l = rib < L_DIM ? rib : L_DIM - 1;
    aoff[mi] = (b * C_DIM) * L_DIM + l;
  }
  const int h0 = ntp * 64 + mcol;               // + ni*16

  f32x4 acc[2][4];
  #pragma unroll
  for (int mi = 0; mi < 2; ++mi)
    #pragma unroll
    for (int ni = 0; ni < 4; ++ni)
      acc[mi][ni] = (f32x4){0.f, 0.f, 0.f, 0.f};

  #pragma unroll
  for (int ks = 0; ks < 4; ++ks) {
    const int k0 = kq * 128 + ks * 32 + g * 8;  // this lane's 8 k's
    bf16x8 afr[2], bfr[4];
    #pragma unroll
    for (int mi = 0; mi < 2; ++mi) {
      const float* __restrict__ pa = f + aoff[mi] + k0 * L_DIM;
      #pragma unroll
      for (int i = 0; i < 8; ++i) afr[mi][i] = bf16r(pa[i * L_DIM]);
    }
    #pragma unroll
    for (int ni = 0; ni < 4; ++ni) {            // A shared across 4 n-frags
      const float* __restrict__ pb = W + k0 * HID + h0 + ni * 16;
      #pragma unroll
      for (int i = 0; i < 8; ++i) bfr[ni][i] = bf16r(pb[i * HID]);
    }
    #pragma unroll
    for (int mi = 0; mi < 2; ++mi)
      #pragma unroll
      for (int ni = 0; ni < 4; ++ni)
        acc[mi][ni] = __builtin_amdgcn_mfma_f32_16x16x32_bf16(
            afr[mi], bfr[ni], acc[mi][ni], 0, 0, 0);
  }

  // tree-combine 4 k-quarter waves (32 floats/lane, idx = mi*16 + ni*4 + reg)
  __shared__ float comb[2][64][33];             // 16.9 KB
  if (kq >= 2) {
    #pragma unroll
    for (int mi = 0; mi < 2; ++mi)
      #pragma unroll
      for (int ni = 0; ni < 4; ++ni)
        *(float4*)&comb[kq - 2][lane][mi * 16 + ni * 4] = *(float4*)&acc[mi][ni];
  }
  __syncthreads();
  if (kq < 2) {
    #pragma unroll
    for (int mi = 0; mi < 2; ++mi)
      #pragma unroll
      for (int ni = 0; ni < 4; ++ni) {
        const float4 o = *(const float4*)&comb[kq][lane][mi * 16 + ni * 4];
        acc[mi][ni][0] += o.x; acc[mi][ni][1] += o.y;
        acc[mi][ni][2] += o.z; acc[mi][ni][3] += o.w;
      }
  }
  __syncthreads();
  if (kq == 1) {
    #pragma unroll
    for (int mi = 0; mi < 2; ++mi)
      #pragma unroll
      for (int ni = 0; ni < 4; ++ni)
        *(float4*)&comb[0][lane][mi * 16 + ni * 4] = *(float4*)&acc[mi][ni];
  }
  __syncthreads();
  if (kq == 0) {
    // C/D layout (verified): col = lane&15, row = g*4 + reg
    #pragma unroll
    for (int mi = 0; mi < 2; ++mi) {
      const int rib0 = mt * 32 + mi * 16 + g * 4;
      #pragma unroll
      for (int ni = 0; ni < 4; ++ni) {
        const int h = h0 + ni * 16;
        const float bias = side ? 0.0f : b1[h];
        const float4 o = *(const float4*)&comb[0][lane][mi * 16 + ni * 4];
        const float v0 = acc[mi][ni][0] + o.x + bias;
        const float v1 = acc[mi][ni][1] + o.y + bias;
        const float v2 = acc[mi][ni][2] + o.z + bias;
        const float v3 = acc[mi][ni][3] + o.w + bias;
        if (rib0 + 0 < L_DIM) p[(b * L_DIM + rib0 + 0) * HID + h] = (_Float16)v0;
        if (rib0 + 1 < L_DIM) p[(b * L_DIM + rib0 + 1) * HID + h] = (_Float16)v1;
        if (rib0 + 2 < L_DIM) p[(b * L_DIM + rib0 + 2) * HID + h] = (_Float16)v2;
        if (rib0 + 3 < L_DIM) p[(b * L_DIM + rib0 + 3) * HID + h] = (_Float16)v3;
      }
    }
  }
}

// Phase 2 (r16 tiling, packed-fp16 body): bid&7 = b -> XCD-local;
// wave = 14 i x 14 j; per 4 channels: pk_add + pk_max + fdot2 (fp32 accum)
// = 6 instrs vs 12 scalar-fp32 -> pair VALU halves.
// Block-sum -> ONE atomicAdd into out[b].
__global__ __launch_bounds__(256) void pair_kernel(
    const _Float16* __restrict__ p1, const _Float16* __restrict__ p2,
    const float* __restrict__ W2, float* __restrict__ out) {
  const int lane = threadIdx.x & 63;
  const int w    = threadIdx.x >> 6;
  const int b    = blockIdx.x & 7;              // XCD-co-located batch
  const int idx  = blockIdx.x >> 3;             // 0..48
  const int r4   = idx * 4 + w;                 // 0..195
  const int jc   = r4 / ROWS;                   // 0..13
  const int wi   = r4 % ROWS;                   // 0..13

  const float4 wf = *(const float4*)(W2 + lane * 4);
  const f16x2 wlo = {(_Float16)wf.x, (_Float16)wf.y};
  const f16x2 whi = {(_Float16)wf.z, (_Float16)wf.w};
  const f16x2 z2  = {(_Float16)0.f, (_Float16)0.f};

  const _Float16* __restrict__ p1b = p1 + (b * L_DIM) * HID + lane * 4;

  f16x2 alo[ROWS], ahi[ROWS];
  #pragma unroll
  for (int k = 0; k < ROWS; ++k) {
    const f16x4 av = *(const f16x4*)(p1b + (wi + k * ROWS) * HID);  // i = wi+k*14
    alo[k] = __builtin_shufflevector(av, av, 0, 1);
    ahi[k] = __builtin_shufflevector(av, av, 2, 3);
  }

  float s[ROWS];
  #pragma unroll
  for (int k = 0; k < ROWS; ++k) s[k] = 0.0f;

  const f16x4* __restrict__ vp =
      (const f16x4*)(p2 + (b * L_DIM + jc * JCL) * HID) + lane;

#define PAIR_BODY(vv)                                                     \
  {                                                                       \
    const f16x2 vlo = __builtin_shufflevector((vv), (vv), 0, 1);          \
    const f16x2 vhi = __builtin_shufflevector((vv), (vv), 2, 3);          \
    _Pragma("unroll")                                                     \
    for (int k = 0; k < ROWS; ++k) {                                      \
      f16x2 rlo = alo[k] + vlo;                                           \
      f16x2 rhi = ahi[k] + vhi;                                           \
      rlo = __builtin_elementwise_max(rlo, z2);                           \
      rhi = __builtin_elementwise_max(rhi, z2);                           \
      s[k] = __builtin_amdgcn_fdot2(rlo, wlo,                             \
               __builtin_amdgcn_fdot2(rhi, whi, s[k], false), false);     \
    }                                                                     \
  }

  // two 7-deep batches: 7 loads in flight, then compute
  f16x4 vv[7];
  #pragma unroll
  for (int j = 0; j < 7; ++j) vv[j] = vp[j * (HID / 4)];
  #pragma unroll
  for (int j = 0; j < 7; ++j) PAIR_BODY(vv[j]);
  #pragma unroll
  for (int j = 0; j < 7; ++j) vv[j] = vp[(7 + j) * (HID / 4)];
  #pragma unroll
  for (int j = 0; j < 7; ++j) PAIR_BODY(vv[j]);
#undef PAIR_BODY

  // collapse rows (13 adds), then one 6-step wave reduce
  float t = 0.0f;
  #pragma unroll
  for (int k = 0; k < ROWS; ++k) t += s[k];
  #pragma unroll
  for (int off = 32; off > 0; off >>= 1) t += __shfl_down(t, off);

  __shared__ float sred[4];
  if (lane == 0) sred[w] = t;
  __syncthreads();
  if (threadIdx.x == 0)
    atomicAdd(&out[b], sred[0] + sred[1] + sred[2] + sred[3]);  // 392 total
}

extern "C" void kernel_launch(void* const* d_in, const int* in_sizes, int n_in,
                              void* d_out, int out_size, void* d_ws, size_t ws_size,
                              hipStream_t stream) {
  const float* f1 = (const float*)d_in[0];   // [B, C, 14, 14]
  const float* f2 = (const float*)d_in[1];
  const float* W1 = (const float*)d_in[2];   // [2C, HID]
  const float* b1 = (const float*)d_in[3];   // [HID]
  const float* W2 = (const float*)d_in[4];   // [HID, 1]
  const float* b2 = (const float*)d_in[5];   // [1]
  float* out = (float*)d_out;                // [B, 1]

  _Float16* p1 = (_Float16*)d_ws;
  _Float16* p2 = p1 + P_ELEMS;

  gemm_p_mfma<<<GEMM_BLOCKS, 256, 0, stream>>>(f1, f2, W1, b1, b2, p1, p2, out);

  pair_kernel<<<PAIR_BLOCKS, 256, 0, stream>>>(p1, p2, W2, out);
}

// Round 21
// 22.392 us; speedup vs baseline: 1.3287x; 1.0189x over previous
//
#include <hip/hip_runtime.h>

typedef __attribute__((ext_vector_type(8))) short bf16x8;
typedef __attribute__((ext_vector_type(4))) float f32x4;
typedef _Float16 f16x2 __attribute__((ext_vector_type(2)));
typedef _Float16 f16x4 __attribute__((ext_vector_type(4)));
typedef _Float16 f16x8 __attribute__((ext_vector_type(8)));

#define C_DIM 512
#define HID   256
#define B_DIM 8
#define L_DIM 196
#define GEMM_BLOCKS 448         // 8 b x 7 mt x 2 side x 4 ntp (64-wide n)
#define ROWS  14                // i-rows per wave (pair)
#define NJC   14
#define JCL   14
#define PAIR_BLOCKS ((B_DIM*NJC*ROWS)/4)    // 392 = 49*8
#define P_ELEMS (B_DIM*L_DIM*HID)

// f32 -> bf16 bits, round-to-nearest (ties up)
__device__ __forceinline__ short bf16r(float x) {
  unsigned u = __builtin_bit_cast(unsigned, x);
  return (short)((u + 0x8000u) >> 16);
}

// Phase 1 (r20 structure; epilogue re-staged through LDS for coalesced 16B
// stores): MFMA bf16, K-split x4, XCD-local (bid&7 = b). 32m x 64n tile.
__global__ __launch_bounds__(256) void gemm_p_mfma(
    const float* __restrict__ f1, const float* __restrict__ f2,
    const float* __restrict__ W1, const float* __restrict__ b1,
    const float* __restrict__ b2,
    _Float16* __restrict__ p1, _Float16* __restrict__ p2,
    float* __restrict__ out) {
  // init output accumulators (pair_kernel atomicAdds into them)
  if (blockIdx.x == 0 && threadIdx.x < B_DIM)
    out[threadIdx.x] = (float)(L_DIM * L_DIM) * b2[0];

  const int b    = blockIdx.x & 7;              // XCD-co-located batch
  const int idx  = blockIdx.x >> 3;             // 0..55
  const int ms   = idx >> 2;                    // 0..13
  const int ntp  = idx & 3;                     // 0..3 (64-wide n tile)
  const int side = ms & 1;
  const int mt   = ms >> 1;                     // m-tile within batch, 0..6

  const float* __restrict__ f = side ? f2 : f1;
  const float* __restrict__ W = W1 + side * C_DIM * HID;
  _Float16* __restrict__ p = side ? p2 : p1;

  const int tid  = threadIdx.x;
  const int kq   = tid >> 6;                    // wave = k-quarter 0..3
  const int lane = tid & 63;
  const int g    = lane >> 4;                   // k-subgroup 0..3
  const int mcol = lane & 15;

  int aoff[2];
  #pragma unroll
  for (int mi = 0; mi < 2; ++mi) {
    const int rib = mt * 32 + mi * 16 + mcol;   // 0..223 (tail clamped)
    const int l = rib < L_DIM ? rib : L_DIM - 1;
    aoff[mi] = (b * C_DIM) * L_DIM + l;
  }
  const int h0 = ntp * 64 + mcol;               // + ni*16

  f32x4 acc[2][4];
  #pragma unroll
  for (int mi = 0; mi < 2; ++mi)
    #pragma unroll
    for (int ni = 0; ni < 4; ++ni)
      acc[mi][ni] = (f32x4){0.f, 0.f, 0.f, 0.f};

  #pragma unroll
  for (int ks = 0; ks < 4; ++ks) {
    const int k0 = kq * 128 + ks * 32 + g * 8;  // this lane's 8 k's
    bf16x8 afr[2], bfr[4];
    #pragma unroll
    for (int mi = 0; mi < 2; ++mi) {
      const float* __restrict__ pa = f + aoff[mi] + k0 * L_DIM;
      #pragma unroll
      for (int i = 0; i < 8; ++i) afr[mi][i] = bf16r(pa[i * L_DIM]);
    }
    #pragma unroll
    for (int ni = 0; ni < 4; ++ni) {            // A shared across 4 n-frags
      const float* __restrict__ pb = W + k0 * HID + h0 + ni * 16;
      #pragma unroll
      for (int i = 0; i < 8; ++i) bfr[ni][i] = bf16r(pb[i * HID]);
    }
    #pragma unroll
    for (int mi = 0; mi < 2; ++mi)
      #pragma unroll
      for (int ni = 0; ni < 4; ++ni)
        acc[mi][ni] = __builtin_amdgcn_mfma_f32_16x16x32_bf16(
            afr[mi], bfr[ni], acc[mi][ni], 0, 0, 0);
  }

  // tree-combine 4 k-quarter waves (32 floats/lane, idx = mi*16 + ni*4 + reg)
  __shared__ float comb[2][64][33];             // 16.9 KB
  __shared__ _Float16 pst[32][68];              // 4.25 KB (pad 68: bank-free)
  if (kq >= 2) {
    #pragma unroll
    for (int mi = 0; mi < 2; ++mi)
      #pragma unroll
      for (int ni = 0; ni < 4; ++ni)
        *(float4*)&comb[kq - 2][lane][mi * 16 + ni * 4] = *(float4*)&acc[mi][ni];
  }
  __syncthreads();
  if (kq < 2) {
    #pragma unroll
    for (int mi = 0; mi < 2; ++mi)
      #pragma unroll
      for (int ni = 0; ni < 4; ++ni) {
        const float4 o = *(const float4*)&comb[kq][lane][mi * 16 + ni * 4];
        acc[mi][ni][0] += o.x; acc[mi][ni][1] += o.y;
        acc[mi][ni][2] += o.z; acc[mi][ni][3] += o.w;
      }
  }
  __syncthreads();
  if (kq == 1) {
    #pragma unroll
    for (int mi = 0; mi < 2; ++mi)
      #pragma unroll
      for (int ni = 0; ni < 4; ++ni)
        *(float4*)&comb[0][lane][mi * 16 + ni * 4] = *(float4*)&acc[mi][ni];
  }
  __syncthreads();
  if (kq == 0) {
    // C/D layout (verified): col = lane&15, row = g*4 + reg.
    // Stage finals (f16, +bias) into pst[row][col]; banks conflict-free
    // (bank = 8g + 2reg + mcol/2 + 8ni covers all 32).
    #pragma unroll
    for (int mi = 0; mi < 2; ++mi) {
      const int row0 = mi * 16 + g * 4;         // local row 0..31
      #pragma unroll
      for (int ni = 0; ni < 4; ++ni) {
        const int col = ni * 16 + mcol;         // local col 0..63
        const float bias = side ? 0.0f : b1[ntp * 64 + col];
        const float4 o = *(const float4*)&comb[0][lane][mi * 16 + ni * 4];
        pst[row0 + 0][col] = (_Float16)(acc[mi][ni][0] + o.x + bias);
        pst[row0 + 1][col] = (_Float16)(acc[mi][ni][1] + o.y + bias);
        pst[row0 + 2][col] = (_Float16)(acc[mi][ni][2] + o.z + bias);
        pst[row0 + 3][col] = (_Float16)(acc[mi][ni][3] + o.w + bias);
      }
    }
  }
  __syncthreads();

  // cooperative coalesced store: thread -> (row = tid>>3, oct = tid&7), 16B
  {
    const int row = tid >> 3;                   // 0..31
    const int oct = tid & 7;                    // 0..7 (8 f16 each)
    const int rib = mt * 32 + row;
    if (rib < L_DIM) {                          // only mt==6 masks
      f16x8 v;
      #pragma unroll
      for (int i = 0; i < 8; ++i) v[i] = pst[row][oct * 8 + i];
      *(f16x8*)(p + (b * L_DIM + rib) * HID + ntp * 64 + oct * 8) = v;
    }
  }
}

// Phase 2 (r20 exact): bid&7 = b -> XCD-local; wave = 14 i x 14 j;
// packed-fp16 body (pk_add + pk_max + fdot2, fp32 accum);
// block-sum -> ONE atomicAdd into out[b].
__global__ __launch_bounds__(256) void pair_kernel(
    const _Float16* __restrict__ p1, const _Float16* __restrict__ p2,
    const float* __restrict__ W2, float* __restrict__ out) {
  const int lane = threadIdx.x & 63;
  const int w    = threadIdx.x >> 6;
  const int b    = blockIdx.x & 7;              // XCD-co-located batch
  const int idx  = blockIdx.x >> 3;             // 0..48
  const int r4   = idx * 4 + w;                 // 0..195
  const int jc   = r4 / ROWS;                   // 0..13
  const int wi   = r4 % ROWS;                   // 0..13

  const float4 wf = *(const float4*)(W2 + lane * 4);
  const f16x2 wlo = {(_Float16)wf.x, (_Float16)wf.y};
  const f16x2 whi = {(_Float16)wf.z, (_Float16)wf.w};
  const f16x2 z2  = {(_Float16)0.f, (_Float16)0.f};

  const _Float16* __restrict__ p1b = p1 + (b * L_DIM) * HID + lane * 4;

  f16x2 alo[ROWS], ahi[ROWS];
  #pragma unroll
  for (int k = 0; k < ROWS; ++k) {
    const f16x4 av = *(const f16x4*)(p1b + (wi + k * ROWS) * HID);  // i = wi+k*14
    alo[k] = __builtin_shufflevector(av, av, 0, 1);
    ahi[k] = __builtin_shufflevector(av, av, 2, 3);
  }

  float s[ROWS];
  #pragma unroll
  for (int k = 0; k < ROWS; ++k) s[k] = 0.0f;

  const f16x4* __restrict__ vp =
      (const f16x4*)(p2 + (b * L_DIM + jc * JCL) * HID) + lane;

#define PAIR_BODY(vv)                                                     \
  {                                                                       \
    const f16x2 vlo = __builtin_shufflevector((vv), (vv), 0, 1);          \
    const f16x2 vhi = __builtin_shufflevector((vv), (vv), 2, 3);          \
    _Pragma("unroll")                                                     \
    for (int k = 0; k < ROWS; ++k) {                                      \
      f16x2 rlo = alo[k] + vlo;                                           \
      f16x2 rhi = ahi[k] + vhi;                                           \
      rlo = __builtin_elementwise_max(rlo, z2);                           \
      rhi = __builtin_elementwise_max(rhi, z2);                           \
      s[k] = __builtin_amdgcn_fdot2(rlo, wlo,                             \
               __builtin_amdgcn_fdot2(rhi, whi, s[k], false), false);     \
    }                                                                     \
  }

  // two 7-deep batches: 7 loads in flight, then compute
  f16x4 vv[7];
  #pragma unroll
  for (int j = 0; j < 7; ++j) vv[j] = vp[j * (HID / 4)];
  #pragma unroll
  for (int j = 0; j < 7; ++j) PAIR_BODY(vv[j]);
  #pragma unroll
  for (int j = 0; j < 7; ++j) vv[j] = vp[(7 + j) * (HID / 4)];
  #pragma unroll
  for (int j = 0; j < 7; ++j) PAIR_BODY(vv[j]);
#undef PAIR_BODY

  // collapse rows (13 adds), then one 6-step wave reduce
  float t = 0.0f;
  #pragma unroll
  for (int k = 0; k < ROWS; ++k) t += s[k];
  #pragma unroll
  for (int off = 32; off > 0; off >>= 1) t += __shfl_down(t, off);

  __shared__ float sred[4];
  if (lane == 0) sred[w] = t;
  __syncthreads();
  if (threadIdx.x == 0)
    atomicAdd(&out[b], sred[0] + sred[1] + sred[2] + sred[3]);  // 392 total
}

extern "C" void kernel_launch(void* const* d_in, const int* in_sizes, int n_in,
                              void* d_out, int out_size, void* d_ws, size_t ws_size,
                              hipStream_t stream) {
  const float* f1 = (const float*)d_in[0];   // [B, C, 14, 14]
  const float* f2 = (const float*)d_in[1];
  const float* W1 = (const float*)d_in[2];   // [2C, HID]
  const float* b1 = (const float*)d_in[3];   // [HID]
  const float* W2 = (const float*)d_in[4];   // [HID, 1]
  const float* b2 = (const float*)d_in[5];   // [1]
  float* out = (float*)d_out;                // [B, 1]

  _Float16* p1 = (_Float16*)d_ws;
  _Float16* p2 = p1 + P_ELEMS;

  gemm_p_mfma<<<GEMM_BLOCKS, 256, 0, stream>>>(f1, f2, W1, b1, b2, p1, p2, out);

  pair_kernel<<<PAIR_BLOCKS, 256, 0, stream>>>(p1, p2, W2, out);
}